// Round 1
// baseline (189.644 us; speedup 1.0000x reference)
//
#include <hip/hip_runtime.h>
#include <math.h>

// Problem constants (from reference setup_inputs)
static constexpr int B_TOTAL = 131072;
static constexpr int M_MOD   = 14;    // NB_MOD_MAX + 2
static constexpr int C_DIM   = 128;   // CONCEPT_N
static constexpr int D_IN    = 3;

// One 64-lane wave per batch element; 4 waves (256 threads) per block.
// Each lane owns 2 of the 128 concept columns (float2 loads).
__global__ __launch_bounds__(256) void impact_kernel(
    const int*   __restrict__ user_ids,
    const int*   __restrict__ item_ids,
    const int*   __restrict__ concept_ids,
    const float* __restrict__ users_emb,   // (USER_N, 128)
    const float* __restrict__ item_resp,   // (ITEM_N * 14, 3)
    const float* __restrict__ W,           // (128, 3, 128)
    const int*   __restrict__ nb_mod,      // (ITEM_N,)
    float*       __restrict__ out)         // (B,)
{
    const int lane = threadIdx.x & 63;
    const int wid  = threadIdx.x >> 6;
    const int b    = blockIdx.x * 4 + wid;

    // Wave-uniform ids -> force SGPR so table reads become scalar loads.
    const int uid = __builtin_amdgcn_readfirstlane(user_ids[b]);
    const int iid = __builtin_amdgcn_readfirstlane(item_ids[b]);
    const int cid = __builtin_amdgcn_readfirstlane(concept_ids[b]);
    const int nb  = nb_mod[iid];           // uniform -> s_load

    // u row: 128 floats, 8 B per lane, fully coalesced.
    const float2  u  = ((const float2*)(users_emb + (size_t)uid * C_DIM))[lane];
    // W_t = W[cid]: (3, 128). Row d at float2 offset d*64.
    const float2* wp = (const float2*)(W + (size_t)cid * D_IN * C_DIM);
    const float2  w0 = wp[lane];
    const float2  w1 = wp[64 + lane];
    const float2  w2 = wp[128 + lane];

    // Item response rows for this item (uniform base -> scalar loads).
    const float* pr = item_resp + (size_t)iid * (M_MOD * D_IN);

    float best  = 3.4e38f;
    int   bestj = 1;
#pragma unroll
    for (int j = 1; j <= 12; ++j) {
        const float p0 = pr[j * 3 + 0];
        const float p1 = pr[j * 3 + 1];
        const float p2 = pr[j * 3 + 2];
        // im_emb[j] on this lane's two columns
        const float ix = fmaf(p0, w0.x, fmaf(p1, w1.x, p2 * w2.x));
        const float iy = fmaf(p0, w0.y, fmaf(p1, w1.y, p2 * w2.y));
        const float dx = u.x - ix;
        const float dy = u.y - iy;
        float part = fmaf(dx, dx, dy * dy);
        // Butterfly reduce across 64 lanes -> every lane holds full sum.
#pragma unroll
        for (int off = 32; off; off >>= 1)
            part += __shfl_xor(part, off, 64);
        // Valid j are [1, nb]; ascending scan + strict '<' reproduces
        // jnp.argmin's first-index tiebreak.
        const bool better = (j <= nb) && (part < best);
        best  = better ? part : best;
        bestj = better ? j : bestj;
    }

    if (lane == 0)
        out[b] = (float)(bestj - 1) / (float)(nb - 1) + 1.0f;
}

extern "C" void kernel_launch(void* const* d_in, const int* in_sizes, int n_in,
                              void* d_out, int out_size, void* d_ws, size_t ws_size,
                              hipStream_t stream) {
    const int*   user_ids    = (const int*)d_in[0];
    const int*   item_ids    = (const int*)d_in[1];
    const int*   concept_ids = (const int*)d_in[2];
    const float* users_emb   = (const float*)d_in[3];
    const float* item_resp   = (const float*)d_in[4];
    const float* W           = (const float*)d_in[5];
    // d_in[6] = mask: unused — validity recomputed from nb_modalities.
    const int*   nb_mod      = (const int*)d_in[7];
    float*       out         = (float*)d_out;

    dim3 grid(B_TOTAL / 4), block(256);
    impact_kernel<<<grid, block, 0, stream>>>(user_ids, item_ids, concept_ids,
                                              users_emb, item_resp, W, nb_mod, out);
}

// Round 2
// 139.336 us; speedup vs baseline: 1.3611x; 1.3611x over previous
//
#include <hip/hip_runtime.h>
#include <math.h>

// Problem constants (from reference setup_inputs)
static constexpr int B_TOTAL = 131072;
static constexpr int M_MOD   = 14;    // NB_MOD_MAX + 2
static constexpr int C_DIM   = 128;   // CONCEPT_N

// 16 lanes per batch element, 4 elements per 64-lane wave, 16 per block.
// Each lane owns 8 of the 128 concept columns: c in {4s..4s+3, 64+4s..64+4s+3}
// where s = lane&15. Reduction is 4 xor-shuffle stages (8,4,2,1), intra-group.
__global__ __launch_bounds__(256) void impact_kernel(
    const int*   __restrict__ user_ids,
    const int*   __restrict__ item_ids,
    const int*   __restrict__ concept_ids,
    const float* __restrict__ users_emb,   // (USER_N, 128)
    const float* __restrict__ item_resp,   // (ITEM_N * 14, 3)
    const float* __restrict__ W,           // (128, 3, 128)
    const int*   __restrict__ nb_mod,      // (ITEM_N,)
    float*       __restrict__ out)         // (B,)
{
    const int s = threadIdx.x & 15;                    // sublane within group
    const int b = blockIdx.x * 16 + (threadIdx.x >> 4); // element id

    const int uid = user_ids[b];
    const int iid = item_ids[b];
    const int cid = concept_ids[b];
    const int nb  = nb_mod[iid];

    // u row: 512 B over 16 lanes -> 2 x float4 per lane, coalesced 256 B runs.
    const float4* up = (const float4*)(users_emb + (size_t)uid * C_DIM);
    const float4 ua = up[s], ub = up[s + 16];

    // W_t = W[cid]: 3 rows x 512 B, same split.
    const float4* wp = (const float4*)(W + (size_t)cid * 3 * C_DIM);
    const float4 w0a = wp[s],          w0b = wp[16 + s];
    const float4 w1a = wp[32 + s],     w1b = wp[48 + s];
    const float4 w2a = wp[64 + s],     w2b = wp[80 + s];

    // Item response rows (group-uniform address; L1/L2 hot, 4 addrs/wave).
    const float* pr = item_resp + (size_t)iid * (M_MOD * 3);

    float best  = 3.4e38f;
    int   bestj = 1;

#define ACC4(U, A0, A1, A2)                                                    \
    do {                                                                       \
        float im_, d_;                                                         \
        im_ = fmaf(p0, A0.x, fmaf(p1, A1.x, p2 * A2.x));                       \
        d_ = U.x - im_; acc = fmaf(d_, d_, acc);                               \
        im_ = fmaf(p0, A0.y, fmaf(p1, A1.y, p2 * A2.y));                       \
        d_ = U.y - im_; acc = fmaf(d_, d_, acc);                               \
        im_ = fmaf(p0, A0.z, fmaf(p1, A1.z, p2 * A2.z));                       \
        d_ = U.z - im_; acc = fmaf(d_, d_, acc);                               \
        im_ = fmaf(p0, A0.w, fmaf(p1, A1.w, p2 * A2.w));                       \
        d_ = U.w - im_; acc = fmaf(d_, d_, acc);                               \
    } while (0)

#pragma unroll
    for (int j = 1; j <= 12; ++j) {
        const float p0 = pr[j * 3 + 0];
        const float p1 = pr[j * 3 + 1];
        const float p2 = pr[j * 3 + 2];
        float acc = 0.0f;
        ACC4(ua, w0a, w1a, w2a);
        ACC4(ub, w0b, w1b, w2b);
        // 4-stage butterfly within the 16-lane group (offsets < 16 stay
        // inside the group under xor).
#pragma unroll
        for (int off = 8; off; off >>= 1)
            acc += __shfl_xor(acc, off, 64);
        // Valid j in [1, nb]; ascending scan + strict '<' = first-index
        // tiebreak, matching jnp.argmin.
        const bool better = (j <= nb) && (acc < best);
        best  = better ? acc : best;
        bestj = better ? j : bestj;
    }
#undef ACC4

    if (s == 0)
        out[b] = (float)(bestj - 1) / (float)(nb - 1) + 1.0f;
}

extern "C" void kernel_launch(void* const* d_in, const int* in_sizes, int n_in,
                              void* d_out, int out_size, void* d_ws, size_t ws_size,
                              hipStream_t stream) {
    const int*   user_ids    = (const int*)d_in[0];
    const int*   item_ids    = (const int*)d_in[1];
    const int*   concept_ids = (const int*)d_in[2];
    const float* users_emb   = (const float*)d_in[3];
    const float* item_resp   = (const float*)d_in[4];
    const float* W           = (const float*)d_in[5];
    // d_in[6] = mask: unused — validity recomputed from nb_modalities.
    const int*   nb_mod      = (const int*)d_in[7];
    float*       out         = (float*)d_out;

    dim3 grid(B_TOTAL / 16), block(256);
    impact_kernel<<<grid, block, 0, stream>>>(user_ids, item_ids, concept_ids,
                                              users_emb, item_resp, W, nb_mod, out);
}

// Round 3
// 111.504 us; speedup vs baseline: 1.7008x; 1.2496x over previous
//
#include <hip/hip_runtime.h>
#include <math.h>

// Problem constants (from reference setup_inputs)
static constexpr int B_TOTAL = 131072;
static constexpr int M_MOD   = 14;    // NB_MOD_MAX + 2
static constexpr int C_DIM   = 128;   // CONCEPT_N

// One 16-lane group per batch element, 4 elements/wave, 16/block.
// Algebra: argmin_j ||u - im_j||^2 = argmin_j ( P_j^T G P_j - 2 P_j . v )
// with v = W_t u (3-vec), G = W_t W_t^T (3x3 Gram); ||u||^2 is j-invariant.
// Lane s owns 8 concept columns {4s..4s+3, 64+4s..64+4s+3}; v and G are
// butterfly-reduced over the group; then lane s scores modality j=s+1 and a
// fminf butterfly + ballot/ctz picks the first-index argmin (jnp tiebreak).
__global__ __launch_bounds__(256) void impact_kernel(
    const int*   __restrict__ user_ids,
    const int*   __restrict__ item_ids,
    const int*   __restrict__ concept_ids,
    const float* __restrict__ users_emb,   // (USER_N, 128)
    const float* __restrict__ item_resp,   // (ITEM_N * 14, 3)
    const float* __restrict__ W,           // (128, 3, 128)
    const int*   __restrict__ nb_mod,      // (ITEM_N,)
    float*       __restrict__ out)         // (B,)
{
    const int s = threadIdx.x & 15;                     // sublane in group
    const int b = blockIdx.x * 16 + (threadIdx.x >> 4); // element id

    const int uid = user_ids[b];
    const int iid = item_ids[b];
    const int cid = concept_ids[b];
    const int nb  = nb_mod[iid];

    // u row: 2 x float4 per lane (256 B coalesced runs per group).
    const float4* up = (const float4*)(users_emb + (size_t)uid * C_DIM);
    const float4 uA = up[s], uB = up[s + 16];
    // W_t = W[cid]: 3 rows x 512 B.
    const float4* wp = (const float4*)(W + (size_t)cid * 3 * C_DIM);
    const float4 w0a = wp[s],      w0b = wp[16 + s];
    const float4 w1a = wp[32 + s], w1b = wp[48 + s];
    const float4 w2a = wp[64 + s], w2b = wp[80 + s];

    // Accumulate v = W_t u and Gram G = W_t W_t^T over this lane's 8 cols.
    float v0 = 0.f, v1 = 0.f, v2 = 0.f;
    float g00 = 0.f, g01 = 0.f, g02 = 0.f, g11 = 0.f, g12 = 0.f, g22 = 0.f;
#define COL(uc, a0, a1, a2)                                                    \
    do {                                                                       \
        v0  = fmaf((a0), (uc), v0);  v1  = fmaf((a1), (uc), v1);               \
        v2  = fmaf((a2), (uc), v2);                                            \
        g00 = fmaf((a0), (a0), g00); g01 = fmaf((a0), (a1), g01);              \
        g02 = fmaf((a0), (a2), g02); g11 = fmaf((a1), (a1), g11);              \
        g12 = fmaf((a1), (a2), g12); g22 = fmaf((a2), (a2), g22);              \
    } while (0)
    COL(uA.x, w0a.x, w1a.x, w2a.x);
    COL(uA.y, w0a.y, w1a.y, w2a.y);
    COL(uA.z, w0a.z, w1a.z, w2a.z);
    COL(uA.w, w0a.w, w1a.w, w2a.w);
    COL(uB.x, w0b.x, w1b.x, w2b.x);
    COL(uB.y, w0b.y, w1b.y, w2b.y);
    COL(uB.z, w0b.z, w1b.z, w2b.z);
    COL(uB.w, w0b.w, w1b.w, w2b.w);
#undef COL

    // Butterfly-reduce the 9 partials across the 16-lane group (all lanes
    // end with identical full sums).
#pragma unroll
    for (int off = 8; off; off >>= 1) {
        v0  += __shfl_xor(v0,  off, 64);
        v1  += __shfl_xor(v1,  off, 64);
        v2  += __shfl_xor(v2,  off, 64);
        g00 += __shfl_xor(g00, off, 64);
        g01 += __shfl_xor(g01, off, 64);
        g02 += __shfl_xor(g02, off, 64);
        g11 += __shfl_xor(g11, off, 64);
        g12 += __shfl_xor(g12, off, 64);
        g22 += __shfl_xor(g22, off, 64);
    }

    // Lane s scores modality j = s+1 (valid iff j <= nb; nb >= 2 so j=1,2
    // always valid -> min is finite).
    float m = INFINITY;
    if (s < 12 && (s + 1) <= nb) {
        const float* pj = item_resp + ((size_t)iid * M_MOD + (s + 1)) * 3;
        const float p0 = pj[0], p1 = pj[1], p2 = pj[2];
        const float dot = fmaf(p0, v0, fmaf(p1, v1, p2 * v2));
        float q = p0 * p0 * g00;
        q = fmaf(p1 * p1, g11, q);
        q = fmaf(p2 * p2, g22, q);
        q = fmaf(2.0f * p0 * p1, g01, q);
        q = fmaf(2.0f * p0 * p2, g02, q);
        q = fmaf(2.0f * p1 * p2, g12, q);
        m = fmaf(-2.0f, dot, q);
    }
    // Group-wide min, then first-set-bit for jnp.argmin's lowest-index tie rule.
    float bm = m;
#pragma unroll
    for (int off = 8; off; off >>= 1)
        bm = fminf(bm, __shfl_xor(bm, off, 64));
    const unsigned long long mask = __ballot(m == bm);
    if (s == 0) {
        const int group = (threadIdx.x >> 4) & 3;
        const unsigned slice = (unsigned)((mask >> (group * 16)) & 0xffffu);
        const int jm1 = __builtin_ctz(slice);   // lane s ↔ j=s+1, so ctz = j-1
        out[b] = (float)jm1 / (float)(nb - 1) + 1.0f;
    }
}

extern "C" void kernel_launch(void* const* d_in, const int* in_sizes, int n_in,
                              void* d_out, int out_size, void* d_ws, size_t ws_size,
                              hipStream_t stream) {
    const int*   user_ids    = (const int*)d_in[0];
    const int*   item_ids    = (const int*)d_in[1];
    const int*   concept_ids = (const int*)d_in[2];
    const float* users_emb   = (const float*)d_in[3];
    const float* item_resp   = (const float*)d_in[4];
    const float* W           = (const float*)d_in[5];
    // d_in[6] = mask: unused — validity recomputed from nb_modalities.
    const int*   nb_mod      = (const int*)d_in[7];
    float*       out         = (float*)d_out;

    dim3 grid(B_TOTAL / 16), block(256);
    impact_kernel<<<grid, block, 0, stream>>>(user_ids, item_ids, concept_ids,
                                              users_emb, item_resp, W, nb_mod, out);
}